// Round 6
// baseline (3141.241 us; speedup 1.0000x reference)
//
#include <hip/hip_runtime.h>

#define V_N 20000
#define E_N 100000
#define NODE_IN_F 128
#define EDGE_IN_F 128
#define H 64
#define EDGE_HID 128
#define OUT_F 64
#define STEPS 9

typedef __attribute__((ext_vector_type(8))) short bf16x8;
typedef __attribute__((ext_vector_type(4))) float f32x4;

__device__ __forceinline__ unsigned short f2bf(float f) {
    union { float f; unsigned int u; } v; v.f = f;
    unsigned int u = v.u;
    unsigned int r = (u + 0x7fffu + ((u >> 16) & 1u)) >> 16;  // RNE
    return (unsigned short)r;
}

__device__ __forceinline__ float dot4(float4 w, float4 x) {
    return w.x * x.x + w.y * x.y + w.z * x.z + w.w * x.w;
}

// h0 = relu(nf@w1.T+b1)@w2.T+b2 (V,64) fp32; zero agg; hb = h0-row @ b_e2-matrix
__global__ __launch_bounds__(64) void k_project(
    const float* __restrict__ nf,
    const float* __restrict__ w1, const float* __restrict__ b1,
    const float* __restrict__ w2, const float* __restrict__ b2,
    const float* __restrict__ b2e,
    float* __restrict__ h, float* __restrict__ agg, float* __restrict__ hb)
{
    int v = blockIdx.x, t = threadIdx.x;
    __shared__ float x[NODE_IN_F], tm[H];
    const float* row = nf + (size_t)v * NODE_IN_F;
    x[t] = row[t];
    x[t + 64] = row[t + 64];
    agg[(size_t)v * H + t] = 0.f;
    __syncthreads();
    float acc = b1[t];
    const float4* wr = (const float4*)(w1 + (size_t)t * NODE_IN_F);
    #pragma unroll
    for (int q = 0; q < NODE_IN_F / 4; ++q) acc += dot4(wr[q], *(const float4*)&x[q * 4]);
    tm[t] = fmaxf(acc, 0.f);
    __syncthreads();
    float acc2 = b2[t];
    const float4* wr2 = (const float4*)(w2 + (size_t)t * H);
    #pragma unroll
    for (int q = 0; q < H / 4; ++q) acc2 += dot4(wr2[q], *(const float4*)&tm[q * 4]);
    h[(size_t)v * H + t] = acc2;
    __syncthreads();
    x[t] = acc2;           // reuse x as h-row
    __syncthreads();
    float acc3 = 0.f;
    for (int i = 0; i < H; ++i) acc3 += x[i] * b2e[i * 64 + t];
    hb[(size_t)v * H + t] = acc3;
}

// g = relu(ef @ w_e1.T + b_e1) -> (E,128) bf16. 32 edges/block.
__global__ __launch_bounds__(256) void k_edge_g(
    const float* __restrict__ ef,
    const float* __restrict__ w1, const float* __restrict__ b1,
    unsigned short* __restrict__ g)
{
    int tid = threadIdx.x;
    int e0 = blockIdx.x * 32;
    int c = tid & 127, eg = tid >> 7;
    __shared__ float xe[32][132];
    for (int idx = tid; idx < 1024; idx += 256) {
        int e = idx >> 5, kq = idx & 31;
        float4 v = *(const float4*)(ef + (size_t)(e0 + e) * EDGE_IN_F + kq * 4);
        *(float4*)&xe[e][kq * 4] = v;
    }
    __syncthreads();
    float acc[16];
    #pragma unroll
    for (int j = 0; j < 16; ++j) acc[j] = b1[c];
    const float4* wr = (const float4*)(w1 + (size_t)c * EDGE_IN_F);
    for (int kb = 0; kb < EDGE_IN_F / 4; ++kb) {
        float4 w = wr[kb];
        #pragma unroll
        for (int j = 0; j < 16; ++j) {
            float4 x = *(const float4*)&xe[eg * 16 + j][kb * 4];
            acc[j] += dot4(w, x);
        }
    }
    #pragma unroll
    for (int j = 0; j < 16; ++j)
        g[(size_t)(e0 + eg * 16 + j) * EDGE_HID + c] = f2bf(fmaxf(acc[j], 0.f));
}

// w_e2 fp32 -> bf16 (4096x128, 1 MB)
__global__ __launch_bounds__(256) void k_w2bf(
    const float* __restrict__ w2, unsigned short* __restrict__ w2b)
{
    int idx = blockIdx.x * 256 + threadIdx.x;
    float4 v = *(const float4*)(w2 + (size_t)idx * 4);
    ushort4 o;
    o.x = f2bf(v.x); o.y = f2bf(v.y); o.z = f2bf(v.z); o.w = f2bf(v.w);
    *(ushort4*)(w2b + (size_t)idx * 4) = o;
}

// Fused NNConv message + scatter. 64 edges/block (4 groups of 16), 4 waves:
// wave wv covers o in [wv*16, wv*16+16) for all 64 edges.
// Reordered contraction (kb outer, exact):
//   msg[e,o] = sum_kb sum_i h[src,i] * mfma16x16x32(g[e, kb-slice], w2b[i*64+o, kb-slice])
// Inner iteration: 4 INDEPENDENT MFMAs (one per edge-group, fresh d, no chains)
// + 16 scale-FMAs. B single-fragment pipeline depth 8 (wrap-indexed, branchless).
// Registers: A 16 + B 32 + msg 16 -> ~3-4 waves/SIMD (was 2 at depth-4/kb-inner).
// Layouts (verified): A[m=lane&15][k=q*8+j], B lane n = row n over k,
// D col=lane&15 (o), row=q*4+r (e within 16-group).
__global__ __launch_bounds__(256) void k_msg_fused(
    const float* __restrict__ h, const unsigned short* __restrict__ g,
    const unsigned short* __restrict__ w2b, const float* __restrict__ hb,
    const int* __restrict__ src, const int* __restrict__ dst,
    float* __restrict__ agg)
{
    int tid = threadIdx.x;
    int wv = tid >> 6, lane = tid & 63;
    int m = lane & 15, q = lane >> 4;
    int e0 = blockIdx.x * 64;
    int o0 = wv * 16;
    __shared__ float h_t[64][68];      // h_t[i][e]; stride 68 floats
    __shared__ int src_s[64], dst_s[64];
    if (tid < 64) {
        int ee = e0 + tid; if (ee > E_N - 1) ee = E_N - 1;
        src_s[tid] = src[ee]; dst_s[tid] = dst[ee];
    }
    __syncthreads();
    for (int idx = tid; idx < 64 * 64; idx += 256) {
        int e = idx >> 6, i = idx & 63;
        h_t[i][e] = h[(size_t)src_s[e] * H + i];
    }
    // edge-group A row pointers (clamped for tail block)
    const unsigned short* ga[4];
    #pragma unroll
    for (int eg = 0; eg < 4; ++eg) {
        int er = e0 + eg * 16 + m; if (er > E_N - 1) er = E_N - 1;
        ga[eg] = g + (size_t)er * EDGE_HID + q * 8;
    }
    __syncthreads();
    f32x4 msg[4] = {{0.f,0.f,0.f,0.f},{0.f,0.f,0.f,0.f},{0.f,0.f,0.f,0.f},{0.f,0.f,0.f,0.f}};
    const unsigned short* pb = w2b + (size_t)(o0 + m) * EDGE_HID + q * 8;

    for (int kb = 0; kb < 4; ++kb) {
        bf16x8 a0 = *(const bf16x8*)(ga[0] + kb * 32);
        bf16x8 a1 = *(const bf16x8*)(ga[1] + kb * 32);
        bf16x8 a2 = *(const bf16x8*)(ga[2] + kb * 32);
        bf16x8 a3 = *(const bf16x8*)(ga[3] + kb * 32);
        const unsigned short* pbk = pb + kb * 32;

#define LOADB(B, I) { B = *(const bf16x8*)(pbk + (size_t)((I) & 63) * 8192); }
#define COMPUTE(I, B) { \
    f32x4 d0 = {0.f,0.f,0.f,0.f}, d1 = {0.f,0.f,0.f,0.f}; \
    f32x4 d2 = {0.f,0.f,0.f,0.f}, d3 = {0.f,0.f,0.f,0.f}; \
    d0 = __builtin_amdgcn_mfma_f32_16x16x32_bf16(a0, B, d0, 0, 0, 0); \
    d1 = __builtin_amdgcn_mfma_f32_16x16x32_bf16(a1, B, d1, 0, 0, 0); \
    d2 = __builtin_amdgcn_mfma_f32_16x16x32_bf16(a2, B, d2, 0, 0, 0); \
    d3 = __builtin_amdgcn_mfma_f32_16x16x32_bf16(a3, B, d3, 0, 0, 0); \
    float4 h0 = *(const float4*)&h_t[(I)][q * 4]; \
    float4 h1 = *(const float4*)&h_t[(I)][16 + q * 4]; \
    float4 h2 = *(const float4*)&h_t[(I)][32 + q * 4]; \
    float4 h3 = *(const float4*)&h_t[(I)][48 + q * 4]; \
    msg[0][0] += h0.x * d0[0]; msg[0][1] += h0.y * d0[1]; \
    msg[0][2] += h0.z * d0[2]; msg[0][3] += h0.w * d0[3]; \
    msg[1][0] += h1.x * d1[0]; msg[1][1] += h1.y * d1[1]; \
    msg[1][2] += h1.z * d1[2]; msg[1][3] += h1.w * d1[3]; \
    msg[2][0] += h2.x * d2[0]; msg[2][1] += h2.y * d2[1]; \
    msg[2][2] += h2.z * d2[2]; msg[2][3] += h2.w * d2[3]; \
    msg[3][0] += h3.x * d3[0]; msg[3][1] += h3.y * d3[1]; \
    msg[3][2] += h3.z * d3[2]; msg[3][3] += h3.w * d3[3]; }

        bf16x8 b0, b1v, b2v, b3, b4, b5, b6, b7;
        LOADB(b0, 0) LOADB(b1v, 1) LOADB(b2v, 2) LOADB(b3, 3)
        LOADB(b4, 4) LOADB(b5, 5) LOADB(b6, 6) LOADB(b7, 7)
        for (int ii = 0; ii < 64; ii += 8) {
            COMPUTE(ii + 0, b0)  LOADB(b0, ii + 8)
            COMPUTE(ii + 1, b1v) LOADB(b1v, ii + 9)
            COMPUTE(ii + 2, b2v) LOADB(b2v, ii + 10)
            COMPUTE(ii + 3, b3)  LOADB(b3, ii + 11)
            COMPUTE(ii + 4, b4)  LOADB(b4, ii + 12)
            COMPUTE(ii + 5, b5)  LOADB(b5, ii + 13)
            COMPUTE(ii + 6, b6)  LOADB(b6, ii + 14)
            COMPUTE(ii + 7, b7)  LOADB(b7, ii + 15)
        }
#undef LOADB
#undef COMPUTE
    }

    int o = o0 + m;
    #pragma unroll
    for (int eg = 0; eg < 4; ++eg) {
        #pragma unroll
        for (int r = 0; r < 4; ++r) {
            int el = eg * 16 + q * 4 + r;
            if (e0 + el < E_N) {
                float v = msg[eg][r] + hb[(size_t)src_s[el] * H + o];
                atomicAdd(&agg[(size_t)dst_s[el] * H + o], v);
            }
        }
    }
}

// GRU over 16 nodes/block; x=relu(agg+b_conv); agg re-zeroed; epilogue: hb = newh @ b_e2
__global__ __launch_bounds__(256) void k_gru(
    float* __restrict__ agg, const float* __restrict__ b_conv,
    const float* __restrict__ w_ih, const float* __restrict__ w_hh,
    const float* __restrict__ b_ih, const float* __restrict__ b_hh,
    const float* __restrict__ b2e,
    float* __restrict__ h, float* __restrict__ hb)
{
    int tid = threadIdx.x;
    int o = tid & 63, grp = tid >> 6;
    int vbase = blockIdx.x * 16;
    __shared__ float xl[16][68], hl[16][68];
    for (int idx = tid; idx < 16 * 64; idx += 256) {
        int n = idx >> 6, i = idx & 63;
        size_t p = (size_t)(vbase + n) * H + i;
        float a = agg[p];
        agg[p] = 0.f;
        xl[n][i] = fmaxf(a + b_conv[i], 0.f);
        hl[n][i] = h[p];
    }
    __syncthreads();
    float gir[4], giz[4], gin[4], ghr[4], ghz[4], ghn[4];
    #pragma unroll
    for (int n = 0; n < 4; ++n) {
        gir[n] = b_ih[o];       ghr[n] = b_hh[o];
        giz[n] = b_ih[64 + o];  ghz[n] = b_hh[64 + o];
        gin[n] = b_ih[128 + o]; ghn[n] = b_hh[128 + o];
    }
    const float4* wir = (const float4*)(w_ih + (size_t)o * H);
    const float4* wiz = (const float4*)(w_ih + (size_t)(64 + o) * H);
    const float4* win = (const float4*)(w_ih + (size_t)(128 + o) * H);
    const float4* whr = (const float4*)(w_hh + (size_t)o * H);
    const float4* whz = (const float4*)(w_hh + (size_t)(64 + o) * H);
    const float4* whn = (const float4*)(w_hh + (size_t)(128 + o) * H);
    #pragma unroll 4
    for (int qq = 0; qq < H / 4; ++qq) {
        float4 a1 = wir[qq], a2 = wiz[qq], a3 = win[qq];
        float4 c1 = whr[qq], c2 = whz[qq], c3 = whn[qq];
        #pragma unroll
        for (int n = 0; n < 4; ++n) {
            float4 xv = *(const float4*)&xl[grp * 4 + n][qq * 4];
            float4 hv = *(const float4*)&hl[grp * 4 + n][qq * 4];
            gir[n] += dot4(a1, xv); giz[n] += dot4(a2, xv); gin[n] += dot4(a3, xv);
            ghr[n] += dot4(c1, hv); ghz[n] += dot4(c2, hv); ghn[n] += dot4(c3, hv);
        }
    }
    float newh[4];
    #pragma unroll
    for (int n = 0; n < 4; ++n) {
        float hv = hl[grp * 4 + n][o];
        float r = 1.f / (1.f + __expf(-(gir[n] + ghr[n])));
        float z = 1.f / (1.f + __expf(-(giz[n] + ghz[n])));
        float na = gin[n] + r * ghn[n];
        float tn = 1.f - 2.f / (__expf(2.f * na) + 1.f);   // tanh
        newh[n] = (1.f - z) * tn + z * hv;
        h[(size_t)(vbase + grp * 4 + n) * H + o] = newh[n];
    }
    __syncthreads();                 // xl dead; reuse for new h
    #pragma unroll
    for (int n = 0; n < 4; ++n) xl[grp * 4 + n][o] = newh[n];
    __syncthreads();
    float hbacc[4] = {0.f, 0.f, 0.f, 0.f};
    for (int i = 0; i < H; ++i) {
        float w = b2e[i * 64 + o];
        #pragma unroll
        for (int n = 0; n < 4; ++n) hbacc[n] += xl[grp * 4 + n][i] * w;
    }
    #pragma unroll
    for (int n = 0; n < 4; ++n)
        hb[(size_t)(vbase + grp * 4 + n) * H + o] = hbacc[n];
}

// out = relu(h @ w_d1.T + b_d1) @ w_d2.T + b_d2  -> fp32
__global__ __launch_bounds__(64) void k_decoder(
    const float* __restrict__ h,
    const float* __restrict__ w1, const float* __restrict__ b1,
    const float* __restrict__ w2, const float* __restrict__ b2,
    float* __restrict__ out)
{
    int v = blockIdx.x, t = threadIdx.x;
    __shared__ float hl[H], tl[H];
    hl[t] = h[(size_t)v * H + t];
    __syncthreads();
    float acc = b1[t];
    const float4* wr = (const float4*)(w1 + (size_t)t * H);
    #pragma unroll
    for (int q = 0; q < H / 4; ++q) acc += dot4(wr[q], *(const float4*)&hl[q * 4]);
    tl[t] = fmaxf(acc, 0.f);
    __syncthreads();
    float acc2 = b2[t];
    const float4* wr2 = (const float4*)(w2 + (size_t)t * H);
    #pragma unroll
    for (int q = 0; q < H / 4; ++q) acc2 += dot4(wr2[q], *(const float4*)&tl[q * 4]);
    out[(size_t)v * OUT_F + t] = acc2;
}

extern "C" void kernel_launch(void* const* d_in, const int* in_sizes, int n_in,
                              void* d_out, int out_size, void* d_ws, size_t ws_size,
                              hipStream_t stream) {
    const float* nf     = (const float*)d_in[0];
    const float* ef     = (const float*)d_in[1];
    const int* src      = (const int*)d_in[2];
    const int* dst      = (const int*)d_in[3];
    const float* w_p1   = (const float*)d_in[4];
    const float* b_p1   = (const float*)d_in[5];
    const float* w_p2   = (const float*)d_in[6];
    const float* b_p2   = (const float*)d_in[7];
    const float* w_e1   = (const float*)d_in[8];
    const float* b_e1   = (const float*)d_in[9];
    const float* w_e2   = (const float*)d_in[10];
    const float* b_e2   = (const float*)d_in[11];
    const float* b_conv = (const float*)d_in[12];
    const float* w_ih   = (const float*)d_in[13];
    const float* w_hh   = (const float*)d_in[14];
    const float* b_ih   = (const float*)d_in[15];
    const float* b_hh   = (const float*)d_in[16];
    const float* w_d1   = (const float*)d_in[17];
    const float* b_d1   = (const float*)d_in[18];
    const float* w_d2   = (const float*)d_in[19];
    const float* b_d2   = (const float*)d_in[20];

    // workspace layout (total 42,008,576 B):
    //   g    : E*128 bf16 = 25,600,000
    //   w2b  : 4096*128 bf16 = 1,048,576
    //   h    : V*64 f32 = 5,120,000
    //   agg  : V*64 f32 = 5,120,000
    //   hb   : V*64 f32 = 5,120,000
    char* ws = (char*)d_ws;
    unsigned short* g   = (unsigned short*)(ws);
    unsigned short* w2b = (unsigned short*)(ws + 25600000LL);
    float* h            = (float*)(ws + 26648576LL);
    float* agg          = (float*)(ws + 31768576LL);
    float* hb           = (float*)(ws + 36888576LL);

    k_project<<<V_N, 64, 0, stream>>>(nf, w_p1, b_p1, w_p2, b_p2, b_e2, h, agg, hb);
    k_edge_g<<<E_N / 32, 256, 0, stream>>>(ef, w_e1, b_e1, g);
    k_w2bf<<<512, 256, 0, stream>>>(w_e2, w2b);
    for (int s = 0; s < STEPS; ++s) {
        k_msg_fused<<<(E_N + 63) / 64, 256, 0, stream>>>(h, g, w2b, hb, src, dst, agg);
        k_gru<<<V_N / 16, 256, 0, stream>>>(agg, b_conv, w_ih, w_hh, b_ih, b_hh, b_e2, h, hb);
    }
    k_decoder<<<V_N, 64, 0, stream>>>(h, w_d1, b_d1, w_d2, b_d2, (float*)d_out);
}